// Round 6
// baseline (559.579 us; speedup 1.0000x reference)
//
#include <hip/hip_runtime.h>
#include <hip/hip_bf16.h>

typedef unsigned short u16;
typedef short short8 __attribute__((ext_vector_type(8)));
typedef short bf16x4 __attribute__((ext_vector_type(4)));
typedef float f32x4 __attribute__((ext_vector_type(4)));

#define B_SZ 4
#define T_SEQ 2048
#define DMODEL 1024
#define NH 16
#define HD 64
#define QKV_ELEMS 8388608ull  // B*NH*T*HD
#define QSCALE (0.125f * 1.44269504f)   // HD^-0.5 * log2(e), folded into Q

__device__ __forceinline__ u16 f2bf(float f) {
    __hip_bfloat16 h = __float2bfloat16(f);
    return __builtin_bit_cast(u16, h);
}

// async global->LDS, 16B/lane; lane i lands at base + 16*i (wave-uniform base).
__device__ __forceinline__ void gload16(const void* g, void* l) {
    __builtin_amdgcn_global_load_lds(
        (const __attribute__((address_space(1))) unsigned int*)g,
        (__attribute__((address_space(3))) unsigned int*)l, 16, 0, 0);
}

// ---------------------------------------------------------------------------
__global__ __launch_bounds__(256) void cast_x_kernel(
    const float4* __restrict__ x, u16* __restrict__ xb)
{
    const int i = blockIdx.x * 256 + threadIdx.x;
    const float4 v = x[i];
    union { u16 u[4]; uint2 d; } p;
    p.u[0] = f2bf(v.x); p.u[1] = f2bf(v.y); p.u[2] = f2bf(v.z); p.u[3] = f2bf(v.w);
    *(uint2*)(xb + (size_t)i * 4) = p.d;
}

__global__ __launch_bounds__(256) void tcast_kernel(
    const float* __restrict__ w, u16* __restrict__ wt, int K, int N)
{
    const int n = blockIdx.x * 256 + threadIdx.x;
    const int k0 = blockIdx.y * 256;
    for (int kk = 0; kk < 256; kk += 8) {
        short8 o;
#pragma unroll
        for (int e = 0; e < 8; ++e)
            o[e] = (short)f2bf(w[(size_t)(k0 + kk + e) * N + n]);
        *(short8*)&wt[(size_t)n * K + k0 + kk] = o;
    }
}

// ---------------------------------------------------------------------------
// bf16 MFMA GEMM 128x128xBK64. EPI=0: scatter q (pre-scaled by QSCALE) / k
// into [B,H,T,HD] and V TRANSPOSED into [B,H,HD,T]. EPI=1: fp32 out.
// ---------------------------------------------------------------------------
template <int EPI>
__global__ __launch_bounds__(256) void gemm_kernel(
    const u16* __restrict__ A, const u16* __restrict__ Bt,
    const float* __restrict__ bias, void* __restrict__ outp)
{
    __shared__ u16 As[128 * 64];
    __shared__ u16 Bs[128 * 64];
    const int tid = threadIdx.x;
    const int l = tid & 63;
    const int w = tid >> 6;
    const int wm = w >> 1, wn = w & 1;
    const int m0 = blockIdx.y * 128, n0 = blockIdx.x * 128;
    const int srow = l >> 3;
    const int sch  = (l & 7) ^ srow;
    const int fr = l & 15, fq = l >> 4;

    f32x4 acc[4][4] = {};

    for (int k0 = 0; k0 < 1024; k0 += 64) {
        __syncthreads();
#pragma unroll
        for (int ii = 0; ii < 4; ++ii) {
            const int row = w * 32 + ii * 8;
            gload16(&A[(size_t)(m0 + row + srow) * 1024 + k0 + sch * 8], &As[row * 64]);
            gload16(&Bt[(size_t)(n0 + row + srow) * 1024 + k0 + sch * 8], &Bs[row * 64]);
        }
        __syncthreads();
#pragma unroll
        for (int ks = 0; ks < 2; ++ks) {
            short8 af[4], bf[4];
#pragma unroll
            for (int t = 0; t < 4; ++t) {
                const int ar = wm * 64 + t * 16 + fr;
                af[t] = *(const short8*)&As[ar * 64 + (((ks * 4 + fq) ^ (l & 7)) << 3)];
                const int br = wn * 64 + t * 16 + fr;
                bf[t] = *(const short8*)&Bs[br * 64 + (((ks * 4 + fq) ^ (l & 7)) << 3)];
            }
#pragma unroll
            for (int mt = 0; mt < 4; ++mt)
#pragma unroll
                for (int nt = 0; nt < 4; ++nt)
                    acc[mt][nt] = __builtin_amdgcn_mfma_f32_16x16x32_bf16(
                        af[mt], bf[nt], acc[mt][nt], 0, 0, 0);
        }
    }

    if (EPI == 0) {
        u16* qkv = (u16*)outp;
#pragma unroll
        for (int nt = 0; nt < 4; ++nt) {
            const int n = n0 + wn * 64 + nt * 16 + fr;
            const float bs = bias[n];
            const int which = n >> 10, hh = (n >> 6) & 15, d = n & 63;
            if (which == 2) {
                // V transposed: [b][h][d][t]; lane's 4 r-values are t-contiguous
                u16* dst = qkv + 2 * QKV_ELEMS;
#pragma unroll
                for (int mt = 0; mt < 4; ++mt) {
                    const int m = m0 + wm * 64 + mt * 16 + fq * 4;
                    const int bb = m >> 11, t = m & 2047;
                    bf16x4 ov;
#pragma unroll
                    for (int r = 0; r < 4; ++r) ov[r] = (short)f2bf(acc[mt][nt][r] + bs);
                    *(bf16x4*)&dst[(((size_t)(bb * NH + hh)) * HD + d) * T_SEQ + t] = ov;
                }
            } else {
                const float scl = (which == 0) ? QSCALE : 1.0f;
                u16* dst = qkv + (size_t)which * QKV_ELEMS + (size_t)hh * T_SEQ * HD + d;
#pragma unroll
                for (int mt = 0; mt < 4; ++mt)
#pragma unroll
                    for (int r = 0; r < 4; ++r) {
                        const int m = m0 + wm * 64 + mt * 16 + fq * 4 + r;
                        const int bb = m >> 11, t = m & 2047;
                        dst[(size_t)bb * (NH * T_SEQ * HD) + (size_t)t * HD] =
                            f2bf((acc[mt][nt][r] + bs) * scl);
                    }
            }
        }
    } else {
        float* C = (float*)outp;
#pragma unroll
        for (int nt = 0; nt < 4; ++nt) {
            const int n = n0 + wn * 64 + nt * 16 + fr;
            const float bs = bias[n];
#pragma unroll
            for (int mt = 0; mt < 4; ++mt)
#pragma unroll
                for (int r = 0; r < 4; ++r) {
                    const int m = m0 + wm * 64 + mt * 16 + fq * 4 + r;
                    C[(size_t)m * DMODEL + n] = acc[mt][nt][r] + bs;
                }
        }
    }
}

// ---------------------------------------------------------------------------
// MFMA flash attention — LDS-free, barrier-free. Block = (qi,h,b), 128 q rows.
// Every MFMA fragment is loaded DIRECTLY from global in MFMA register layout:
//   Q/K rows [t][d]: 16B at d = ks*32+fq*8      (B/A-operand of 16x16x32)
//   V^T rows [d][t]: 8B  at t = j0+jt*16+fq*4   (A-operand of 16x16x16_1k)
// P stays in registers (C-layout == B-operand layout of 16x16x16_1k).
// No __syncthreads anywhere; per-wave chains overlap across 12+ waves/CU.
// ---------------------------------------------------------------------------
__global__ __launch_bounds__(256, 3) void attn_kernel(
    const u16* __restrict__ q, const u16* __restrict__ k,
    const u16* __restrict__ vT, u16* __restrict__ y)
{
    const int qi = (gridDim.x - 1) - blockIdx.x;   // big blocks first
    const int hh = blockIdx.y, bb = blockIdx.z;
    const int q0 = qi * 128;
    const size_t hbase = ((size_t)(bb * NH + hh)) * T_SEQ * HD;
    const u16* qb = q + hbase;
    const u16* kb = k + hbase;
    const u16* vTb = vT + hbase;     // [d][t]

    const int tid = threadIdx.x;
    const int l = tid & 63;
    const int w = tid >> 6;
    const int fr = l & 15, fq = l >> 4;

    // Q fragments (B-operand: n=q=fr, k=d=ks*32+fq*8..+7) straight from global
    short8 qf[2][2];
#pragma unroll
    for (int mt = 0; mt < 2; ++mt)
#pragma unroll
        for (int ks = 0; ks < 2; ++ks)
            qf[mt][ks] = *(const short8*)
                &qb[(size_t)(q0 + mt * 64 + w * 16 + fr) * HD + ks * 32 + fq * 8];

    float m_run[2] = {-1e30f, -1e30f}, l_run[2] = {0.f, 0.f};
    f32x4 o_acc[2][4] = {};   // [mt][dt], O^T: row=d, col=q

    const int nkt = 2 * (qi + 1);
    for (int kt = 0; kt < nkt; ++kt) {
        const int j0 = kt * 64;

        // K fragments (A-operand: m=j=fr, k=d) — 16B contiguous per lane
        short8 kf[4][2];
#pragma unroll
        for (int jt = 0; jt < 4; ++jt)
#pragma unroll
            for (int ks = 0; ks < 2; ++ks)
                kf[jt][ks] = *(const short8*)
                    &kb[(size_t)(j0 + jt * 16 + fr) * HD + ks * 32 + fq * 8];

        // V^T fragments (A-operand 16x16x16: m=d=fr, k=j=fq*4..+3) — 8B per lane
        bf16x4 vf[4][4];
#pragma unroll
        for (int dt = 0; dt < 4; ++dt)
#pragma unroll
            for (int jt = 0; jt < 4; ++jt)
                vf[dt][jt] = *(const bf16x4*)
                    &vTb[(size_t)(dt * 16 + fr) * T_SEQ + j0 + jt * 16 + fq * 4];

#pragma unroll
        for (int mt = 0; mt < 2; ++mt) {
            const int qbase = q0 + mt * 64 + w * 16;
            if (j0 >= qbase + 16) continue;      // whole tile masked for this wave

            bool live[4];
#pragma unroll
            for (int jt = 0; jt < 4; ++jt)
                live[jt] = (j0 + jt * 16) <= (qbase + 15);

            f32x4 st[4];
#pragma unroll
            for (int jt = 0; jt < 4; ++jt) {
                st[jt] = f32x4{0.f, 0.f, 0.f, 0.f};
                if (live[jt]) {
                    st[jt] = __builtin_amdgcn_mfma_f32_16x16x32_bf16(
                        kf[jt][0], qf[mt][0], st[jt], 0, 0, 0);
                    st[jt] = __builtin_amdgcn_mfma_f32_16x16x32_bf16(
                        kf[jt][1], qf[mt][1], st[jt], 0, 0, 0);
                }
            }

            const int qg = qbase + fr;
            float mx = -1e30f;
#pragma unroll
            for (int jt = 0; jt < 4; ++jt) {
                if (!live[jt]) continue;
                const bool needMask = (j0 + jt * 16 + 15) > qbase;
#pragma unroll
                for (int r = 0; r < 4; ++r) {
                    float s = st[jt][r];
                    if (needMask) {
                        const int jg = j0 + jt * 16 + fq * 4 + r;
                        if (jg > qg) s = -1e30f;
                    }
                    st[jt][r] = s;
                    mx = fmaxf(mx, s);
                }
            }
            mx = fmaxf(mx, __shfl_xor(mx, 16));
            mx = fmaxf(mx, __shfl_xor(mx, 32));
            const float mn = fmaxf(m_run[mt], mx);
            const float alpha = exp2f(m_run[mt] - mn);
            m_run[mt] = mn;

            float ls = 0.f;
            bf16x4 pk[4];
#pragma unroll
            for (int jt = 0; jt < 4; ++jt) {
                if (!live[jt]) continue;
#pragma unroll
                for (int r = 0; r < 4; ++r) {
                    const float p = exp2f(st[jt][r] - mn);
                    ls += p;
                    pk[jt][r] = (short)f2bf(p);
                }
            }
            ls += __shfl_xor(ls, 16);
            ls += __shfl_xor(ls, 32);
            l_run[mt] = l_run[mt] * alpha + ls;

#pragma unroll
            for (int dt = 0; dt < 4; ++dt) o_acc[mt][dt] *= alpha;

#pragma unroll
            for (int dt = 0; dt < 4; ++dt)
#pragma unroll
                for (int jt = 0; jt < 4; ++jt)
                    if (live[jt])
                        o_acc[mt][dt] = __builtin_amdgcn_mfma_f32_16x16x16bf16_1k(
                            vf[dt][jt], pk[jt], o_acc[mt][dt], 0, 0, 0);
        }
    }

    // write y [B,T,D] bf16; lane holds d=dt*16+fq*4+r, t=q0+mt*64+w*16+fr
#pragma unroll
    for (int mt = 0; mt < 2; ++mt) {
        const float inv = 1.f / l_run[mt];
        const int t = q0 + mt * 64 + w * 16 + fr;
#pragma unroll
        for (int dt = 0; dt < 4; ++dt) {
            bf16x4 ov;
#pragma unroll
            for (int r = 0; r < 4; ++r) ov[r] = (short)f2bf(o_acc[mt][dt][r] * inv);
            *(bf16x4*)&y[((size_t)(bb * T_SEQ + t)) * DMODEL + hh * HD + dt * 16 + fq * 4] = ov;
        }
    }
}

extern "C" void kernel_launch(void* const* d_in, const int* in_sizes, int n_in,
                              void* d_out, int out_size, void* d_ws, size_t ws_size,
                              hipStream_t stream) {
    const float* x      = (const float*)d_in[0];
    const float* w_qkv  = (const float*)d_in[1];
    const float* b_qkv  = (const float*)d_in[2];
    const float* w_proj = (const float*)d_in[3];
    const float* b_proj = (const float*)d_in[4];
    float* out = (float*)d_out;

    u16* xb  = (u16*)d_ws;
    u16* wqT = xb + 8388608;
    u16* wpT = wqT + 3145728;
    u16* qkv = wpT + 1048576;           // q | k | vT
    u16* yb  = qkv + 3 * QKV_ELEMS;

    cast_x_kernel<<<8192, 256, 0, stream>>>((const float4*)x, xb);
    tcast_kernel<<<dim3(12, 4), 256, 0, stream>>>(w_qkv, wqT, 1024, 3072);
    tcast_kernel<<<dim3(4, 4), 256, 0, stream>>>(w_proj, wpT, 1024, 1024);
    gemm_kernel<0><<<dim3(24, 64), 256, 0, stream>>>(xb, wqT, b_qkv, (void*)qkv);
    attn_kernel<<<dim3(T_SEQ / 128, NH, B_SZ), 256, 0, stream>>>(
        qkv, qkv + QKV_ELEMS, qkv + 2 * QKV_ELEMS, yb);
    gemm_kernel<1><<<dim3(8, 64), 256, 0, stream>>>(yb, wpT, b_proj, (void*)out);
}

// Round 7
// 371.266 us; speedup vs baseline: 1.5072x; 1.5072x over previous
//
#include <hip/hip_runtime.h>
#include <hip/hip_bf16.h>

typedef unsigned short u16;
typedef short short8 __attribute__((ext_vector_type(8)));
typedef short bf16x4 __attribute__((ext_vector_type(4)));
typedef float f32x4 __attribute__((ext_vector_type(4)));
typedef float f32x16 __attribute__((ext_vector_type(16)));

#define B_SZ 4
#define T_SEQ 2048
#define DMODEL 1024
#define NH 16
#define HD 64
#define QKV_ELEMS 8388608ull  // B*NH*T*HD
#define QSCALE (0.125f * 1.44269504f)   // HD^-0.5 * log2(e), folded into Q

__device__ __forceinline__ u16 f2bf(float f) {
    __hip_bfloat16 h = __float2bfloat16(f);
    return __builtin_bit_cast(u16, h);
}

// async global->LDS, 16B/lane; lane i lands at base + 16*i (wave-uniform base).
__device__ __forceinline__ void gload16(const void* g, void* l) {
    __builtin_amdgcn_global_load_lds(
        (const __attribute__((address_space(1))) unsigned int*)g,
        (__attribute__((address_space(3))) unsigned int*)l, 16, 0, 0);
}

// ---------------------------------------------------------------------------
__global__ __launch_bounds__(256) void cast_x_kernel(
    const float4* __restrict__ x, u16* __restrict__ xb)
{
    const int i = blockIdx.x * 256 + threadIdx.x;
    const float4 v = x[i];
    union { u16 u[4]; uint2 d; } p;
    p.u[0] = f2bf(v.x); p.u[1] = f2bf(v.y); p.u[2] = f2bf(v.z); p.u[3] = f2bf(v.w);
    *(uint2*)(xb + (size_t)i * 4) = p.d;
}

__global__ __launch_bounds__(256) void tcast_kernel(
    const float* __restrict__ w, u16* __restrict__ wt, int K, int N)
{
    const int n = blockIdx.x * 256 + threadIdx.x;
    const int k0 = blockIdx.y * 256;
    for (int kk = 0; kk < 256; kk += 8) {
        short8 o;
#pragma unroll
        for (int e = 0; e < 8; ++e)
            o[e] = (short)f2bf(w[(size_t)(k0 + kk + e) * N + n]);
        *(short8*)&wt[(size_t)n * K + k0 + kk] = o;
    }
}

// ---------------------------------------------------------------------------
// bf16 MFMA GEMM 128x128xBK64. EPI=0: scatter q (pre-scaled by QSCALE) / k
// into [B,H,T,HD] and V TRANSPOSED into [B,H,HD,T]. EPI=1: fp32 out.
// ---------------------------------------------------------------------------
template <int EPI>
__global__ __launch_bounds__(256) void gemm_kernel(
    const u16* __restrict__ A, const u16* __restrict__ Bt,
    const float* __restrict__ bias, void* __restrict__ outp)
{
    __shared__ u16 As[128 * 64];
    __shared__ u16 Bs[128 * 64];
    const int tid = threadIdx.x;
    const int l = tid & 63;
    const int w = tid >> 6;
    const int wm = w >> 1, wn = w & 1;
    const int m0 = blockIdx.y * 128, n0 = blockIdx.x * 128;
    const int srow = l >> 3;
    const int sch  = (l & 7) ^ srow;
    const int fr = l & 15, fq = l >> 4;

    f32x4 acc[4][4] = {};

    for (int k0 = 0; k0 < 1024; k0 += 64) {
        __syncthreads();
#pragma unroll
        for (int ii = 0; ii < 4; ++ii) {
            const int row = w * 32 + ii * 8;
            gload16(&A[(size_t)(m0 + row + srow) * 1024 + k0 + sch * 8], &As[row * 64]);
            gload16(&Bt[(size_t)(n0 + row + srow) * 1024 + k0 + sch * 8], &Bs[row * 64]);
        }
        __syncthreads();
#pragma unroll
        for (int ks = 0; ks < 2; ++ks) {
            short8 af[4], bf[4];
#pragma unroll
            for (int t = 0; t < 4; ++t) {
                const int ar = wm * 64 + t * 16 + fr;
                af[t] = *(const short8*)&As[ar * 64 + (((ks * 4 + fq) ^ (l & 7)) << 3)];
                const int br = wn * 64 + t * 16 + fr;
                bf[t] = *(const short8*)&Bs[br * 64 + (((ks * 4 + fq) ^ (l & 7)) << 3)];
            }
#pragma unroll
            for (int mt = 0; mt < 4; ++mt)
#pragma unroll
                for (int nt = 0; nt < 4; ++nt)
                    acc[mt][nt] = __builtin_amdgcn_mfma_f32_16x16x32_bf16(
                        af[mt], bf[nt], acc[mt][nt], 0, 0, 0);
        }
    }

    if (EPI == 0) {
        u16* qkv = (u16*)outp;
#pragma unroll
        for (int nt = 0; nt < 4; ++nt) {
            const int n = n0 + wn * 64 + nt * 16 + fr;
            const float bs = bias[n];
            const int which = n >> 10, hh = (n >> 6) & 15, d = n & 63;
            if (which == 2) {
                // V transposed: [b][h][d][t]; lane's 4 r-values are t-contiguous
                u16* dst = qkv + 2 * QKV_ELEMS;
#pragma unroll
                for (int mt = 0; mt < 4; ++mt) {
                    const int m = m0 + wm * 64 + mt * 16 + fq * 4;
                    const int bb = m >> 11, t = m & 2047;
                    bf16x4 ov;
#pragma unroll
                    for (int r = 0; r < 4; ++r) ov[r] = (short)f2bf(acc[mt][nt][r] + bs);
                    *(bf16x4*)&dst[(((size_t)(bb * NH + hh)) * HD + d) * T_SEQ + t] = ov;
                }
            } else {
                const float scl = (which == 0) ? QSCALE : 1.0f;
                u16* dst = qkv + (size_t)which * QKV_ELEMS + (size_t)hh * T_SEQ * HD + d;
#pragma unroll
                for (int mt = 0; mt < 4; ++mt)
#pragma unroll
                    for (int r = 0; r < 4; ++r) {
                        const int m = m0 + wm * 64 + mt * 16 + fq * 4 + r;
                        const int bb = m >> 11, t = m & 2047;
                        dst[(size_t)bb * (NH * T_SEQ * HD) + (size_t)t * HD] =
                            f2bf((acc[mt][nt][r] + bs) * scl);
                    }
            }
        }
    } else {
        float* C = (float*)outp;
#pragma unroll
        for (int nt = 0; nt < 4; ++nt) {
            const int n = n0 + wn * 64 + nt * 16 + fr;
            const float bs = bias[n];
#pragma unroll
            for (int mt = 0; mt < 4; ++mt)
#pragma unroll
                for (int r = 0; r < 4; ++r) {
                    const int m = m0 + wm * 64 + mt * 16 + fq * 4 + r;
                    C[(size_t)m * DMODEL + n] = acc[mt][nt][r] + bs;
                }
        }
    }
}

// ---------------------------------------------------------------------------
// MFMA flash attention, 32x32 tiles. Block = (qi,h,b), 128 q rows; wave w
// owns 32 q rows (one softmax chain). S^T = K Q^T via 32x32x16 (C: col=q,
// row=j=(r&3)+8(r>>2)+4h). Softmax: in-lane over 16 regs + ONE shfl_xor(32).
// PV: C regs 4g..4g+3 feed 32x32x8bf16_1k B-operand directly (k=4h+e) -> no
// LDS round-trip for P. K/V^T double-buffered via global_load_lds.
// ---------------------------------------------------------------------------
__global__ __launch_bounds__(256) void attn_kernel(
    const u16* __restrict__ q, const u16* __restrict__ k,
    const u16* __restrict__ vT, u16* __restrict__ y)
{
    __shared__ u16 Qs[128 * 64];     // 16 KB  [q_row][d], swizzled 128B rows
    __shared__ u16 Ks[2][64 * 64];   // 16 KB  [j][d]
    __shared__ u16 Vs[2][64 * 64];   // 16 KB  [d][t]

    const int qi = (gridDim.x - 1) - blockIdx.x;   // big blocks first
    const int hh = blockIdx.y, bb = blockIdx.z;
    const int q0 = qi * 128;
    const size_t hbase = ((size_t)(bb * NH + hh)) * T_SEQ * HD;
    const u16* qb = q + hbase;
    const u16* kb = k + hbase;
    const u16* vTb = vT + hbase;     // [d][t]

    const int tid = threadIdx.x;
    const int l = tid & 63;
    const int w = tid >> 6;
    const int qn = l & 31;           // q within wave tile
    const int h = l >> 5;            // half-wave
    const int srow = l >> 3;
    const int sch = (l & 7) ^ srow;

    // stage Q (128 rows) + K/V tile 0
#pragma unroll
    for (int ii = 0; ii < 4; ++ii) {
        const int row = w * 32 + ii * 8;
        gload16(&qb[(size_t)(q0 + row + srow) * HD + sch * 8], &Qs[row * 64]);
    }
    {
        const int row = w * 16, row2 = w * 16 + 8;
        gload16(&kb[(size_t)(row + srow) * HD + sch * 8], &Ks[0][row * 64]);
        gload16(&kb[(size_t)(row2 + srow) * HD + sch * 8], &Ks[0][row2 * 64]);
        gload16(&vTb[(size_t)(row + srow) * T_SEQ + sch * 8], &Vs[0][row * 64]);
        gload16(&vTb[(size_t)(row2 + srow) * T_SEQ + sch * 8], &Vs[0][row2 * 64]);
    }
    __syncthreads();

    // hoist Q fragments (B-operand 32x32x16: n=q=qn, k=k16*16+h*8+e)
    short8 qf[4];
    {
        const int qrow = w * 32 + qn;
#pragma unroll
        for (int k16 = 0; k16 < 4; ++k16)
            qf[k16] = *(const short8*)
                &Qs[qrow * 64 + (((k16 * 2 + h) ^ (qrow & 7)) << 3)];
    }

    const int q0w = q0 + w * 32;     // this wave's first q row
    float m_run = -1e30f, l_run = 0.f;
    f32x16 o_acc[2] = {};            // O^T: [dt] d=dt*32+(r&3)+8(r>>2)+4h, col=q=qn

    const int nkt = 2 * (qi + 1);
    for (int kt = 0; kt < nkt; ++kt) {
        if (kt > 0) __syncthreads();
        if (kt + 1 < nkt) {
            const int nb = (kt + 1) & 1;
            const int jj = (kt + 1) * 64;
            const int row = w * 16, row2 = w * 16 + 8;
            gload16(&kb[(size_t)(jj + row + srow) * HD + sch * 8], &Ks[nb][row * 64]);
            gload16(&kb[(size_t)(jj + row2 + srow) * HD + sch * 8], &Ks[nb][row2 * 64]);
            gload16(&vTb[(size_t)(row + srow) * T_SEQ + jj + sch * 8], &Vs[nb][row * 64]);
            gload16(&vTb[(size_t)(row2 + srow) * T_SEQ + jj + sch * 8], &Vs[nb][row2 * 64]);
        }
        const int buf = kt & 1;
        const int j0 = kt * 64;

        if (j0 > q0w + 31) continue;          // whole round masked for this wave
        const int njt = (j0 + 32 <= q0w + 31) ? 2 : 1;   // live 32-j subtiles

        // S^T = K Q^T
        f32x16 st[2];
#pragma unroll
        for (int jt = 0; jt < 2; ++jt) {
            if (jt >= njt) continue;
            f32x16 s = {};
#pragma unroll
            for (int k16 = 0; k16 < 4; ++k16) {
                const int jrow = jt * 32 + qn;
                const short8 kf = *(const short8*)
                    &Ks[buf][jrow * 64 + (((k16 * 2 + h) ^ (jrow & 7)) << 3)];
                s = __builtin_amdgcn_mfma_f32_32x32x16_bf16(kf, qf[k16], s, 0, 0, 0);
            }
            st[jt] = s;
        }

        // causal mask (only needed near the diagonal)
        const int qg = q0w + qn;
        float mx = m_run;
#pragma unroll
        for (int jt = 0; jt < 2; ++jt) {
            if (jt >= njt) continue;
            const bool needMask = (j0 + jt * 32 + 31) > q0w;
            if (needMask) {
#pragma unroll
                for (int r = 0; r < 16; ++r) {
                    const int jg = j0 + jt * 32 + (r & 3) + 8 * (r >> 2) + 4 * h;
                    if (jg > qg) st[jt][r] = -1e30f;
                }
            }
#pragma unroll
            for (int r = 0; r < 16; ++r) mx = fmaxf(mx, st[jt][r]);
        }
        mx = fmaxf(mx, __shfl_xor(mx, 32));   // single cross-lane reduce
        const float alpha = exp2f(m_run - mx);
        m_run = mx;

        float ls = 0.f;
#pragma unroll
        for (int jt = 0; jt < 2; ++jt) {
            if (jt >= njt) continue;
#pragma unroll
            for (int r = 0; r < 16; ++r) {
                const float p = exp2f(st[jt][r] - mx);
                st[jt][r] = p;
                ls += p;
            }
        }
        ls += __shfl_xor(ls, 32);
        l_run = l_run * alpha + ls;

#pragma unroll
        for (int dt = 0; dt < 2; ++dt)
#pragma unroll
            for (int r = 0; r < 16; ++r) o_acc[dt][r] *= alpha;

        // PV: O^T += V^T P^T, P straight from st regs
#pragma unroll
        for (int jt = 0; jt < 2; ++jt) {
            if (jt >= njt) continue;
#pragma unroll
            for (int g = 0; g < 4; ++g) {
                bf16x4 pk;
#pragma unroll
                for (int e = 0; e < 4; ++e) pk[e] = (short)f2bf(st[jt][g * 4 + e]);
#pragma unroll
                for (int dt = 0; dt < 2; ++dt) {
                    const int drow = dt * 32 + qn;
                    const bf16x4 vf = *(const bf16x4*)
                        &Vs[buf][drow * 64 +
                                 (((jt * 4 + g) ^ (drow & 7)) << 3) + h * 4];
                    o_acc[dt] = __builtin_amdgcn_mfma_f32_32x32x8bf16_1k(
                        vf, pk, o_acc[dt], 0, 0, 0);
                }
            }
        }
    }

    // write y [B,T,D] bf16: t = q0w + qn, d = dt*32 + 8g + 4h + e
    const float inv = 1.f / l_run;
    const int t = q0w + qn;
    u16* yrow = y + ((size_t)(bb * T_SEQ + t)) * DMODEL + hh * HD;
#pragma unroll
    for (int dt = 0; dt < 2; ++dt)
#pragma unroll
        for (int g = 0; g < 4; ++g) {
            bf16x4 ov;
#pragma unroll
            for (int e = 0; e < 4; ++e)
                ov[e] = (short)f2bf(o_acc[dt][g * 4 + e] * inv);
            *(bf16x4*)&yrow[dt * 32 + g * 8 + h * 4] = ov;
        }
}

extern "C" void kernel_launch(void* const* d_in, const int* in_sizes, int n_in,
                              void* d_out, int out_size, void* d_ws, size_t ws_size,
                              hipStream_t stream) {
    const float* x      = (const float*)d_in[0];
    const float* w_qkv  = (const float*)d_in[1];
    const float* b_qkv  = (const float*)d_in[2];
    const float* w_proj = (const float*)d_in[3];
    const float* b_proj = (const float*)d_in[4];
    float* out = (float*)d_out;

    u16* xb  = (u16*)d_ws;
    u16* wqT = xb + 8388608;
    u16* wpT = wqT + 3145728;
    u16* qkv = wpT + 1048576;           // q | k | vT
    u16* yb  = qkv + 3 * QKV_ELEMS;

    cast_x_kernel<<<8192, 256, 0, stream>>>((const float4*)x, xb);
    tcast_kernel<<<dim3(12, 4), 256, 0, stream>>>(w_qkv, wqT, 1024, 3072);
    tcast_kernel<<<dim3(4, 4), 256, 0, stream>>>(w_proj, wpT, 1024, 1024);
    gemm_kernel<0><<<dim3(24, 64), 256, 0, stream>>>(xb, wqT, b_qkv, (void*)qkv);
    attn_kernel<<<dim3(T_SEQ / 128, NH, B_SZ), 256, 0, stream>>>(
        qkv, qkv + QKV_ELEMS, qkv + 2 * QKV_ELEMS, yb);
    gemm_kernel<1><<<dim3(8, 64), 256, 0, stream>>>(yb, wpT, b_proj, (void*)out);
}

// Round 8
// 371.063 us; speedup vs baseline: 1.5080x; 1.0005x over previous
//
#include <hip/hip_runtime.h>
#include <hip/hip_bf16.h>

typedef unsigned short u16;
typedef short short8 __attribute__((ext_vector_type(8)));
typedef short bf16x4 __attribute__((ext_vector_type(4)));
typedef float f32x4 __attribute__((ext_vector_type(4)));
typedef float f32x16 __attribute__((ext_vector_type(16)));

#define B_SZ 4
#define T_SEQ 2048
#define DMODEL 1024
#define NH 16
#define HD 64
#define QKV_ELEMS 8388608ull  // B*NH*T*HD
#define QSCALE (0.125f * 1.44269504f)   // HD^-0.5 * log2(e), folded into Q

__device__ __forceinline__ u16 f2bf(float f) {
    __hip_bfloat16 h = __float2bfloat16(f);
    return __builtin_bit_cast(u16, h);
}

// async global->LDS, 16B/lane; lane i lands at base + 16*i (wave-uniform base).
__device__ __forceinline__ void gload16(const void* g, void* l) {
    __builtin_amdgcn_global_load_lds(
        (const __attribute__((address_space(1))) unsigned int*)g,
        (__attribute__((address_space(3))) unsigned int*)l, 16, 0, 0);
}

// ---------------------------------------------------------------------------
__global__ __launch_bounds__(256) void cast_x_kernel(
    const float4* __restrict__ x, u16* __restrict__ xb)
{
    const int i = blockIdx.x * 256 + threadIdx.x;
    const float4 v = x[i];
    union { u16 u[4]; uint2 d; } p;
    p.u[0] = f2bf(v.x); p.u[1] = f2bf(v.y); p.u[2] = f2bf(v.z); p.u[3] = f2bf(v.w);
    *(uint2*)(xb + (size_t)i * 4) = p.d;
}

__global__ __launch_bounds__(256) void tcast_kernel(
    const float* __restrict__ w, u16* __restrict__ wt, int K, int N)
{
    const int n = blockIdx.x * 256 + threadIdx.x;
    const int k0 = blockIdx.y * 256;
    for (int kk = 0; kk < 256; kk += 8) {
        short8 o;
#pragma unroll
        for (int e = 0; e < 8; ++e)
            o[e] = (short)f2bf(w[(size_t)(k0 + kk + e) * N + n]);
        *(short8*)&wt[(size_t)n * K + k0 + kk] = o;
    }
}

// ---------------------------------------------------------------------------
// bf16 MFMA GEMM 128x128xBK64. EPI=0: scatter q (pre-scaled by QSCALE) / k
// into [B,H,T,HD] and V TRANSPOSED into [B,H,HD,T]. EPI=1: fp32 out.
// ---------------------------------------------------------------------------
template <int EPI>
__global__ __launch_bounds__(256) void gemm_kernel(
    const u16* __restrict__ A, const u16* __restrict__ Bt,
    const float* __restrict__ bias, void* __restrict__ outp)
{
    __shared__ u16 As[128 * 64];
    __shared__ u16 Bs[128 * 64];
    const int tid = threadIdx.x;
    const int l = tid & 63;
    const int w = tid >> 6;
    const int wm = w >> 1, wn = w & 1;
    const int m0 = blockIdx.y * 128, n0 = blockIdx.x * 128;
    const int srow = l >> 3;
    const int sch  = (l & 7) ^ srow;
    const int fr = l & 15, fq = l >> 4;

    f32x4 acc[4][4] = {};

    for (int k0 = 0; k0 < 1024; k0 += 64) {
        __syncthreads();
#pragma unroll
        for (int ii = 0; ii < 4; ++ii) {
            const int row = w * 32 + ii * 8;
            gload16(&A[(size_t)(m0 + row + srow) * 1024 + k0 + sch * 8], &As[row * 64]);
            gload16(&Bt[(size_t)(n0 + row + srow) * 1024 + k0 + sch * 8], &Bs[row * 64]);
        }
        __syncthreads();
#pragma unroll
        for (int ks = 0; ks < 2; ++ks) {
            short8 af[4], bf[4];
#pragma unroll
            for (int t = 0; t < 4; ++t) {
                const int ar = wm * 64 + t * 16 + fr;
                af[t] = *(const short8*)&As[ar * 64 + (((ks * 4 + fq) ^ (l & 7)) << 3)];
                const int br = wn * 64 + t * 16 + fr;
                bf[t] = *(const short8*)&Bs[br * 64 + (((ks * 4 + fq) ^ (l & 7)) << 3)];
            }
#pragma unroll
            for (int mt = 0; mt < 4; ++mt)
#pragma unroll
                for (int nt = 0; nt < 4; ++nt)
                    acc[mt][nt] = __builtin_amdgcn_mfma_f32_16x16x32_bf16(
                        af[mt], bf[nt], acc[mt][nt], 0, 0, 0);
        }
    }

    if (EPI == 0) {
        u16* qkv = (u16*)outp;
#pragma unroll
        for (int nt = 0; nt < 4; ++nt) {
            const int n = n0 + wn * 64 + nt * 16 + fr;
            const float bs = bias[n];
            const int which = n >> 10, hh = (n >> 6) & 15, d = n & 63;
            if (which == 2) {
                // V transposed: [b][h][d][t]; lane's 4 r-values are t-contiguous
                u16* dst = qkv + 2 * QKV_ELEMS;
#pragma unroll
                for (int mt = 0; mt < 4; ++mt) {
                    const int m = m0 + wm * 64 + mt * 16 + fq * 4;
                    const int bb = m >> 11, t = m & 2047;
                    bf16x4 ov;
#pragma unroll
                    for (int r = 0; r < 4; ++r) ov[r] = (short)f2bf(acc[mt][nt][r] + bs);
                    *(bf16x4*)&dst[(((size_t)(bb * NH + hh)) * HD + d) * T_SEQ + t] = ov;
                }
            } else {
                const float scl = (which == 0) ? QSCALE : 1.0f;
                u16* dst = qkv + (size_t)which * QKV_ELEMS + (size_t)hh * T_SEQ * HD + d;
#pragma unroll
                for (int mt = 0; mt < 4; ++mt)
#pragma unroll
                    for (int r = 0; r < 4; ++r) {
                        const int m = m0 + wm * 64 + mt * 16 + fq * 4 + r;
                        const int bb = m >> 11, t = m & 2047;
                        dst[(size_t)bb * (NH * T_SEQ * HD) + (size_t)t * HD] =
                            f2bf((acc[mt][nt][r] + bs) * scl);
                    }
            }
        }
    } else {
        float* C = (float*)outp;
#pragma unroll
        for (int nt = 0; nt < 4; ++nt) {
            const int n = n0 + wn * 64 + nt * 16 + fr;
            const float bs = bias[n];
#pragma unroll
            for (int mt = 0; mt < 4; ++mt)
#pragma unroll
                for (int r = 0; r < 4; ++r) {
                    const int m = m0 + wm * 64 + mt * 16 + fq * 4 + r;
                    C[(size_t)m * DMODEL + n] = acc[mt][nt][r] + bs;
                }
        }
    }
}

// ---------------------------------------------------------------------------
// MFMA flash attention, 32x32 tiles, 32 KB LDS (Q staged through the Ks
// double-buffer so the whole 1024-block grid is co-resident: 5 blocks/CU
// capacity vs 4 needed). Wave w owns 32 q rows; softmax is in-lane over 16
// regs + ONE shfl_xor(32). PV feeds P straight from C regs (32x32x8bf16_1k).
// ---------------------------------------------------------------------------
__global__ __launch_bounds__(256) void attn_kernel(
    const u16* __restrict__ q, const u16* __restrict__ k,
    const u16* __restrict__ vT, u16* __restrict__ y)
{
    __shared__ u16 Ks[2][64 * 64];   // 16 KB [j][d]; also Q staging (128 rows)
    __shared__ u16 Vs[2][64 * 64];   // 16 KB [d][t]

    const int qi = (gridDim.x - 1) - blockIdx.x;   // big blocks first
    const int hh = blockIdx.y, bb = blockIdx.z;
    const int q0 = qi * 128;
    const size_t hbase = ((size_t)(bb * NH + hh)) * T_SEQ * HD;
    const u16* qb = q + hbase;
    const u16* kb = k + hbase;
    const u16* vTb = vT + hbase;     // [d][t]

    const int tid = threadIdx.x;
    const int l = tid & 63;
    const int w = tid >> 6;
    const int qn = l & 31;           // q within wave tile
    const int h = l >> 5;            // half-wave
    const int srow = l >> 3;
    const int sch = (l & 7) ^ srow;

    u16* Qstage = &Ks[0][0];         // 16 KB spanning both Ks buffers

    // stage Q (128 rows -> Ks area) + V tile 0
#pragma unroll
    for (int ii = 0; ii < 4; ++ii) {
        const int row = w * 32 + ii * 8;
        gload16(&qb[(size_t)(q0 + row + srow) * HD + sch * 8], &Qstage[row * 64]);
    }
    {
        const int row = w * 16, row2 = w * 16 + 8;
        gload16(&vTb[(size_t)(row + srow) * T_SEQ + sch * 8], &Vs[0][row * 64]);
        gload16(&vTb[(size_t)(row2 + srow) * T_SEQ + sch * 8], &Vs[0][row2 * 64]);
    }
    __syncthreads();   // Q + V0 landed

    // hoist Q fragments (B-operand 32x32x16: n=q=qn, k=k16*16+h*8+e)
    short8 qf[4];
    {
        const int qrow = w * 32 + qn;
#pragma unroll
        for (int k16 = 0; k16 < 4; ++k16)
            qf[k16] = *(const short8*)
                &Qstage[qrow * 64 + (((k16 * 2 + h) ^ (qrow & 7)) << 3)];
    }
    __syncthreads();   // all waves done reading Q; Ks reusable

    // K tile 0
    {
        const int row = w * 16, row2 = w * 16 + 8;
        gload16(&kb[(size_t)(row + srow) * HD + sch * 8], &Ks[0][row * 64]);
        gload16(&kb[(size_t)(row2 + srow) * HD + sch * 8], &Ks[0][row2 * 64]);
    }

    const int q0w = q0 + w * 32;     // this wave's first q row
    float m_run = -1e30f, l_run = 0.f;
    f32x16 o_acc[2] = {};            // O^T: [dt] d=dt*32+(r&3)+8(r>>2)+4h, col=q=qn

    const int nkt = 2 * (qi + 1);
    for (int kt = 0; kt < nkt; ++kt) {
        __syncthreads();   // drains prev gloads (incl. K0) + prev readers done
        if (kt + 1 < nkt) {
            const int nb = (kt + 1) & 1;
            const int jj = (kt + 1) * 64;
            const int row = w * 16, row2 = w * 16 + 8;
            gload16(&kb[(size_t)(jj + row + srow) * HD + sch * 8], &Ks[nb][row * 64]);
            gload16(&kb[(size_t)(jj + row2 + srow) * HD + sch * 8], &Ks[nb][row2 * 64]);
            gload16(&vTb[(size_t)(row + srow) * T_SEQ + jj + sch * 8], &Vs[nb][row * 64]);
            gload16(&vTb[(size_t)(row2 + srow) * T_SEQ + jj + sch * 8], &Vs[nb][row2 * 64]);
        }
        const int buf = kt & 1;
        const int j0 = kt * 64;

        if (j0 > q0w + 31) continue;          // whole round masked for this wave
        const int njt = (j0 + 32 <= q0w + 31) ? 2 : 1;   // live 32-j subtiles

        // S^T = K Q^T
        f32x16 st[2];
#pragma unroll
        for (int jt = 0; jt < 2; ++jt) {
            if (jt >= njt) continue;
            f32x16 s = {};
#pragma unroll
            for (int k16 = 0; k16 < 4; ++k16) {
                const int jrow = jt * 32 + qn;
                const short8 kf = *(const short8*)
                    &Ks[buf][jrow * 64 + (((k16 * 2 + h) ^ (jrow & 7)) << 3)];
                s = __builtin_amdgcn_mfma_f32_32x32x16_bf16(kf, qf[k16], s, 0, 0, 0);
            }
            st[jt] = s;
        }

        // causal mask (only needed near the diagonal)
        const int qg = q0w + qn;
        float mx = m_run;
#pragma unroll
        for (int jt = 0; jt < 2; ++jt) {
            if (jt >= njt) continue;
            const bool needMask = (j0 + jt * 32 + 31) > q0w;
            if (needMask) {
#pragma unroll
                for (int r = 0; r < 16; ++r) {
                    const int jg = j0 + jt * 32 + (r & 3) + 8 * (r >> 2) + 4 * h;
                    if (jg > qg) st[jt][r] = -1e30f;
                }
            }
#pragma unroll
            for (int r = 0; r < 16; ++r) mx = fmaxf(mx, st[jt][r]);
        }
        mx = fmaxf(mx, __shfl_xor(mx, 32));   // single cross-lane reduce
        const float alpha = exp2f(m_run - mx);
        m_run = mx;

        float ls = 0.f;
#pragma unroll
        for (int jt = 0; jt < 2; ++jt) {
            if (jt >= njt) continue;
#pragma unroll
            for (int r = 0; r < 16; ++r) {
                const float p = exp2f(st[jt][r] - mx);
                st[jt][r] = p;
                ls += p;
            }
        }
        ls += __shfl_xor(ls, 32);
        l_run = l_run * alpha + ls;

#pragma unroll
        for (int dt = 0; dt < 2; ++dt)
#pragma unroll
            for (int r = 0; r < 16; ++r) o_acc[dt][r] *= alpha;

        // PV: O^T += V^T P^T, P straight from st regs
#pragma unroll
        for (int jt = 0; jt < 2; ++jt) {
            if (jt >= njt) continue;
#pragma unroll
            for (int g = 0; g < 4; ++g) {
                bf16x4 pk;
#pragma unroll
                for (int e = 0; e < 4; ++e) pk[e] = (short)f2bf(st[jt][g * 4 + e]);
#pragma unroll
                for (int dt = 0; dt < 2; ++dt) {
                    const int drow = dt * 32 + qn;
                    const bf16x4 vf = *(const bf16x4*)
                        &Vs[buf][drow * 64 +
                                 (((jt * 4 + g) ^ (drow & 7)) << 3) + h * 4];
                    o_acc[dt] = __builtin_amdgcn_mfma_f32_32x32x8bf16_1k(
                        vf, pk, o_acc[dt], 0, 0, 0);
                }
            }
        }
    }

    // write y [B,T,D] bf16: t = q0w + qn, d = dt*32 + 8g + 4h + e
    const float inv = 1.f / l_run;
    const int t = q0w + qn;
    u16* yrow = y + ((size_t)(bb * T_SEQ + t)) * DMODEL + hh * HD;
#pragma unroll
    for (int dt = 0; dt < 2; ++dt)
#pragma unroll
        for (int g = 0; g < 4; ++g) {
            bf16x4 ov;
#pragma unroll
            for (int e = 0; e < 4; ++e)
                ov[e] = (short)f2bf(o_acc[dt][g * 4 + e] * inv);
            *(bf16x4*)&yrow[dt * 32 + g * 8 + h * 4] = ov;
        }
}

extern "C" void kernel_launch(void* const* d_in, const int* in_sizes, int n_in,
                              void* d_out, int out_size, void* d_ws, size_t ws_size,
                              hipStream_t stream) {
    const float* x      = (const float*)d_in[0];
    const float* w_qkv  = (const float*)d_in[1];
    const float* b_qkv  = (const float*)d_in[2];
    const float* w_proj = (const float*)d_in[3];
    const float* b_proj = (const float*)d_in[4];
    float* out = (float*)d_out;

    u16* xb  = (u16*)d_ws;
    u16* wqT = xb + 8388608;
    u16* wpT = wqT + 3145728;
    u16* qkv = wpT + 1048576;           // q | k | vT
    u16* yb  = qkv + 3 * QKV_ELEMS;

    cast_x_kernel<<<8192, 256, 0, stream>>>((const float4*)x, xb);
    tcast_kernel<<<dim3(12, 4), 256, 0, stream>>>(w_qkv, wqT, 1024, 3072);
    tcast_kernel<<<dim3(4, 4), 256, 0, stream>>>(w_proj, wpT, 1024, 1024);
    gemm_kernel<0><<<dim3(24, 64), 256, 0, stream>>>(xb, wqT, b_qkv, (void*)qkv);
    attn_kernel<<<dim3(T_SEQ / 128, NH, B_SZ), 256, 0, stream>>>(
        qkv, qkv + QKV_ELEMS, qkv + 2 * QKV_ELEMS, yb);
    gemm_kernel<1><<<dim3(8, 64), 256, 0, stream>>>(yb, wpT, b_proj, (void*)out);
}